// Round 2
// baseline (7054.755 us; speedup 1.0000x reference)
//
#include <hip/hip_runtime.h>
#include <cstddef>

#define BB 256
#define SS 1024
#define VV 288
#define EE 100
#define HH 128
#define G4 512
#define TC 16

__device__ __forceinline__ float sigmoid_f(float x) {
    return __fdividef(1.0f, 1.0f + __expf(-x));
}
__device__ __forceinline__ float tanh_f(float x) {
    x = fminf(fmaxf(x, -15.0f), 15.0f);
    float e = __expf(2.0f * x);
    return __fdividef(e - 1.0f, e + 1.0f);
}

// table[v][j] = bih0[j]+bhh0[j] + sum_e emb[v][e] * Wih0[j][e]
__global__ __launch_bounds__(512) void proj_kernel(
    const float* __restrict__ emb, const float* __restrict__ Wih0,
    const float* __restrict__ bih0, const float* __restrict__ bhh0,
    float* __restrict__ table)
{
    __shared__ float er[EE];
    const int v = blockIdx.x;
    const int j = threadIdx.x;
    for (int e = j; e < EE; e += 512) er[e] = emb[v * EE + e];
    __syncthreads();
    float acc = bih0[j] + bhh0[j];
    const float* wr = Wih0 + j * EE;
#pragma unroll 4
    for (int e = 0; e < EE; e++) acc = fmaf(er[e], wr[e], acc);
    table[v * G4 + j] = acc;
}

// Layer 0. 1024 threads: lanes 2j,2j+1 split the 128-dot for gate j.
// w in 16 float4 regs (64 VGPR) -> no spill at the 128-VGPR cap.
__global__ __launch_bounds__(1024, 4) void lstm0_kernel(
    const int* __restrict__ text, const float* __restrict__ table,
    const float* __restrict__ Whh, float* __restrict__ hout)
{
    __shared__ float h_lds[HH];
    __shared__ float gact[G4];
    const int b = blockIdx.x;
    const int tid = threadIdx.x;
    const int j = tid >> 1;       // gate 0..511
    const int half = tid & 1;     // k-half
    float4 w4[16];
    {
        const float4* ws = (const float4*)(Whh + (size_t)j * HH + 64 * half);
#pragma unroll
        for (int q = 0; q < 16; q++) w4[q] = ws[q];
    }
    if (tid < HH) h_lds[tid] = 0.0f;
    float c = 0.0f;
    const int quarter = j >> 7;
    const int* tptr = text + (size_t)b * SS;
    int tok = tptr[0];
    float gpre = half ? 0.0f : table[(size_t)tok * G4 + j];
    __syncthreads();
    for (int t = 0; t < SS; t++) {
        float g = gpre;
        {
            const int tn = (t + 1 < SS) ? (t + 1) : (SS - 1);
            const int tok2 = tptr[tn];
            gpre = half ? 0.0f : table[(size_t)tok2 * G4 + j];
        }
        const float4* h4 = (const float4*)(h_lds + 64 * half);
#pragma unroll
        for (int q = 0; q < 16; q++) {
            const float4 hv = h4[q];
            g = fmaf(hv.x, w4[q].x, g);
            g = fmaf(hv.y, w4[q].y, g);
            g = fmaf(hv.z, w4[q].z, g);
            g = fmaf(hv.w, w4[q].w, g);
        }
        g += __shfl_xor(g, 1);
        const float a = (quarter == 2) ? tanh_f(g) : sigmoid_f(g);
        if (half == 0) gact[j] = a;
        __syncthreads();
        if (tid < HH) {
            const float gi = gact[tid];
            const float gf = gact[tid + HH];
            const float gg = gact[tid + 2 * HH];
            const float go = gact[tid + 3 * HH];
            c = fmaf(gf, c, gi * gg);
            const float hv = go * tanh_f(c);
            h_lds[tid] = hv;
            hout[((size_t)t * BB + b) * HH + tid] = hv;
        }
        __syncthreads();
    }
}

// Layers 1,2 in-place on hbuf. 1024 threads.
__global__ __launch_bounds__(1024, 4) void lstm12_kernel(
    const float* __restrict__ Wih,   // [512][128] natural layout
    const float* __restrict__ Whh,   // [512][128]
    const float* __restrict__ bih, const float* __restrict__ bhh,
    float* hbuf)
{
    __shared__ float h_lds[HH];
    __shared__ float gact[G4];
    __shared__ float xin[TC][HH];    // prev-layer h chunk, 8 KB
    __shared__ float xg[TC][G4];     // input-proj chunk, 32 KB
    const int b = blockIdx.x;
    const int tid = threadIdx.x;
    const int j = tid >> 1;
    const int half = tid & 1;
    float4 w4[16];
    {
        const float4* ws = (const float4*)(Whh + (size_t)j * HH + 64 * half);
#pragma unroll
        for (int q = 0; q < 16; q++) w4[q] = ws[q];
    }
    const int pj  = tid >> 2;        // 0..255 -> gates 2pj, 2pj+1
    const int ph  = (tid >> 1) & 1;  // k-half for proj
    const int ptg = tid & 1;         // t-half: steps 8*ptg..
    const float bja = bih[2 * pj] + bhh[2 * pj];
    const float bjb = bih[2 * pj + 1] + bhh[2 * pj + 1];
    if (tid < HH) h_lds[tid] = 0.0f;
    float c = 0.0f;
    const int quarter = j >> 7;
    __syncthreads();
    for (int t0 = 0; t0 < SS; t0 += TC) {
        if (tid < 512) {
            const int tt = tid >> 5, q = tid & 31;
            ((float4*)&xin[tt][0])[q] =
                ((const float4*)(hbuf + ((size_t)(t0 + tt) * BB + b) * HH))[q];
        }
        __syncthreads();
        // ---- input projection for this chunk ----
        float acc0[8], acc1[8];
#pragma unroll
        for (int t = 0; t < 8; t++) { acc0[t] = 0.0f; acc1[t] = 0.0f; }
        const float4* wr0 = (const float4*)(Wih + (size_t)(2 * pj) * HH + 64 * ph);
        const float4* wr1 = (const float4*)(Wih + (size_t)(2 * pj + 1) * HH + 64 * ph);
#pragma unroll 4
        for (int kq = 0; kq < 16; kq++) {
            const float4 wa = wr0[kq];
            const float4 wb = wr1[kq];
#pragma unroll
            for (int t = 0; t < 8; t++) {
                const float4 xv = ((const float4*)&xin[8 * ptg + t][0])[16 * ph + kq];
                acc0[t] = fmaf(xv.x, wa.x, acc0[t]);
                acc0[t] = fmaf(xv.y, wa.y, acc0[t]);
                acc0[t] = fmaf(xv.z, wa.z, acc0[t]);
                acc0[t] = fmaf(xv.w, wa.w, acc0[t]);
                acc1[t] = fmaf(xv.x, wb.x, acc1[t]);
                acc1[t] = fmaf(xv.y, wb.y, acc1[t]);
                acc1[t] = fmaf(xv.z, wb.z, acc1[t]);
                acc1[t] = fmaf(xv.w, wb.w, acc1[t]);
            }
        }
#pragma unroll
        for (int t = 0; t < 8; t++) {
            acc0[t] += __shfl_xor(acc0[t], 2);   // combine k-halves (bit1)
            acc1[t] += __shfl_xor(acc1[t], 2);
        }
        if (ph == 0) {
#pragma unroll
            for (int t = 0; t < 8; t++) {
                xg[8 * ptg + t][2 * pj]     = acc0[t] + bja;
                xg[8 * ptg + t][2 * pj + 1] = acc1[t] + bjb;
            }
        }
        __syncthreads();
        // ---- 16 recurrent steps ----
        for (int tt = 0; tt < TC; tt++) {
            float g = half ? 0.0f : xg[tt][j];
            const float4* h4 = (const float4*)(h_lds + 64 * half);
#pragma unroll
            for (int q = 0; q < 16; q++) {
                const float4 hv = h4[q];
                g = fmaf(hv.x, w4[q].x, g);
                g = fmaf(hv.y, w4[q].y, g);
                g = fmaf(hv.z, w4[q].z, g);
                g = fmaf(hv.w, w4[q].w, g);
            }
            g += __shfl_xor(g, 1);
            const float a = (quarter == 2) ? tanh_f(g) : sigmoid_f(g);
            if (half == 0) gact[j] = a;
            __syncthreads();
            if (tid < HH) {
                const float gi = gact[tid];
                const float gf = gact[tid + HH];
                const float gg = gact[tid + 2 * HH];
                const float go = gact[tid + 3 * HH];
                c = fmaf(gf, c, gi * gg);
                const float hv = go * tanh_f(c);
                h_lds[tid] = hv;
                hbuf[((size_t)(t0 + tt) * BB + b) * HH + tid] = hv;
            }
            __syncthreads();
        }
    }
}

// FC head: out[m][n] = dot(h[m], fcW[n]) + fcb[n]; M=262144, N=288, K=128
__global__ __launch_bounds__(256) void fc_kernel(
    const float* __restrict__ hbuf, const float* __restrict__ fcW,
    const float* __restrict__ fcb, float* __restrict__ out)
{
    __shared__ float Ash[128][68];
    __shared__ float Bsh[32][132];
    const int tid = threadIdx.x;
    const size_t mb = (size_t)blockIdx.x * 64;
    const int nb = blockIdx.y * 32;
#pragma unroll
    for (int p = 0; p < 8; p++) {
        const int fi = tid + p * 256;
        const int m = fi >> 5, k4 = fi & 31;
        float4 v = ((const float4*)(hbuf + (mb + m) * HH))[k4];
        Ash[k4*4+0][m] = v.x;
        Ash[k4*4+1][m] = v.y;
        Ash[k4*4+2][m] = v.z;
        Ash[k4*4+3][m] = v.w;
    }
#pragma unroll
    for (int p = 0; p < 4; p++) {
        const int fi = tid + p * 256;
        const int n = fi >> 5, k4 = fi & 31;
        ((float4*)&Bsh[n][0])[k4] = ((const float4*)(fcW + (size_t)(nb + n) * HH))[k4];
    }
    __syncthreads();
    const int tni = tid & 15, tmi = tid >> 4;
    const int m0 = tmi * 4, n0 = tni * 2;
    float a00=0,a01=0,a10=0,a11=0,a20=0,a21=0,a30=0,a31=0;
#pragma unroll 8
    for (int k = 0; k < 128; k++) {
        const float4 av = *((const float4*)&Ash[k][m0]);
        const float b0v = Bsh[n0][k], b1v = Bsh[n0+1][k];
        a00 = fmaf(av.x, b0v, a00); a01 = fmaf(av.x, b1v, a01);
        a10 = fmaf(av.y, b0v, a10); a11 = fmaf(av.y, b1v, a11);
        a20 = fmaf(av.z, b0v, a20); a21 = fmaf(av.z, b1v, a21);
        a30 = fmaf(av.w, b0v, a30); a31 = fmaf(av.w, b1v, a31);
    }
    const float c0 = fcb[nb + n0], c1 = fcb[nb + n0 + 1];
    float* o0 = out + (mb + m0 + 0) * VV + nb + n0;
    float* o1 = out + (mb + m0 + 1) * VV + nb + n0;
    float* o2 = out + (mb + m0 + 2) * VV + nb + n0;
    float* o3 = out + (mb + m0 + 3) * VV + nb + n0;
    *((float2*)o0) = make_float2(a00 + c0, a01 + c1);
    *((float2*)o1) = make_float2(a10 + c0, a11 + c1);
    *((float2*)o2) = make_float2(a20 + c0, a21 + c1);
    *((float2*)o3) = make_float2(a30 + c0, a31 + c1);
}

extern "C" void kernel_launch(void* const* d_in, const int* in_sizes, int n_in,
                              void* d_out, int out_size, void* d_ws, size_t ws_size,
                              hipStream_t stream)
{
    (void)in_sizes; (void)n_in; (void)out_size; (void)ws_size;
    const int*   text = (const int*)  d_in[0];
    const float* emb  = (const float*)d_in[1];
    const float* fcW  = (const float*)d_in[2];
    const float* fcb  = (const float*)d_in[3];
    const float* Wih0 = (const float*)d_in[4];
    const float* Whh0 = (const float*)d_in[5];
    const float* bih0 = (const float*)d_in[6];
    const float* bhh0 = (const float*)d_in[7];
    const float* Wih1 = (const float*)d_in[8];
    const float* Whh1 = (const float*)d_in[9];
    const float* bih1 = (const float*)d_in[10];
    const float* bhh1 = (const float*)d_in[11];
    const float* Wih2 = (const float*)d_in[12];
    const float* Whh2 = (const float*)d_in[13];
    const float* bih2 = (const float*)d_in[14];
    const float* bhh2 = (const float*)d_in[15];
    float* out = (float*)d_out;
    float* ws  = (float*)d_ws;

    float* table = ws;                    // 288*512
    float* hbuf  = table + VV * G4;       // 1024*256*128, reused per layer

    proj_kernel<<<VV, 512, 0, stream>>>(emb, Wih0, bih0, bhh0, table);
    lstm0_kernel<<<BB, 1024, 0, stream>>>(text, table, Whh0, hbuf);
    lstm12_kernel<<<BB, 1024, 0, stream>>>(Wih1, Whh1, bih1, bhh1, hbuf);
    lstm12_kernel<<<BB, 1024, 0, stream>>>(Wih2, Whh2, bih2, bhh2, hbuf);
    fc_kernel<<<dim3(4096, 9), 256, 0, stream>>>(hbuf, fcW, fcb, out);
}